// Round 4
// baseline (856.457 us; speedup 1.0000x reference)
//
#include <hip/hip_runtime.h>
#include <hip/hip_bf16.h>

#define M_DIM 8192
#define K_DIM 4096
#define N_DIM 11008

typedef unsigned short ushort_t;
typedef short s16x8 __attribute__((ext_vector_type(8)));   // 8 bf16 (4 VGPR) MFMA operand
typedef float f32x4 __attribute__((ext_vector_type(4)));   // MFMA accumulator

__device__ __forceinline__ unsigned int f2bf(float f) {
    unsigned int u = __float_as_uint(f);
    u += 0x7FFFu + ((u >> 16) & 1u);   // round-to-nearest-even
    return u >> 16;
}

// ---------- pre-pass 1: x fp32 -> bf16 ----------
__global__ __launch_bounds__(256) void k_cvt_x(const float4* __restrict__ x, uint4* __restrict__ xb) {
    int i = blockIdx.x * 256 + threadIdx.x;
    float4 a = x[i * 2], b = x[i * 2 + 1];
    uint4 o;
    o.x = f2bf(a.x) | (f2bf(a.y) << 16);
    o.y = f2bf(a.z) | (f2bf(a.w) << 16);
    o.z = f2bf(b.x) | (f2bf(b.y) << 16);
    o.w = f2bf(b.z) | (f2bf(b.w) << 16);
    xb[i] = o;
}

// ---------- pre-pass 2: dequant q int32 -> bf16 ----------
__global__ __launch_bounds__(256) void k_deq(const int4* __restrict__ q, const float* __restrict__ sc,
                                             const float* __restrict__ zp, uint4* __restrict__ wb) {
    int i = blockIdx.x * 256 + threadIdx.x;
    int o = i >> 9;
    float s = sc[o], z = zp[o];
    int4 a = q[i * 2], b = q[i * 2 + 1];
    uint4 r;
    r.x = f2bf(((float)a.x - z) * s) | (f2bf(((float)a.y - z) * s) << 16);
    r.y = f2bf(((float)a.z - z) * s) | (f2bf(((float)a.w - z) * s) << 16);
    r.z = f2bf(((float)b.x - z) * s) | (f2bf(((float)b.y - z) * s) << 16);
    r.w = f2bf(((float)b.z - z) * s) | (f2bf(((float)b.w - z) * s) << 16);
    wb[i] = r;
}

// ---------- 256x256 8-phase GEMM: C[m][n] = sum_k A[m][k]*B[n][k] + bias[n] ----------
// LDS swizzle: 16-byte chunk c of row r stores global chunk c ^ (r&7)
// Deep pipeline: group t stages ALL of tile t+2 into buf(t) (same parity);
// each half staged right after its last ds_read. Group-end s_waitcnt vmcnt(8)
// -> tile t+1 (issued a full group = 5-7 phases earlier) landed; tile t+2's
// 8 loads stay in flight across the barrier (T4: never drain in main loop).
using gcptr = const __attribute__((address_space(1))) void*;
using lptr  = __attribute__((address_space(3))) void*;
#define GLD16(gp, lp) __builtin_amdgcn_global_load_lds((gcptr)(gp), (lptr)(lp), 16, 0, 0)
#define BAR() asm volatile("s_barrier" ::: "memory")
#define VMW8() asm volatile("s_waitcnt vmcnt(8)" ::: "memory")
#define VMW0() asm volatile("s_waitcnt vmcnt(0)" ::: "memory")

__global__ __launch_bounds__(512, 2) void k_gemm(const ushort_t* __restrict__ A,
                                                 const ushort_t* __restrict__ B,
                                                 const float* __restrict__ bias,
                                                 float* __restrict__ C) {
    constexpr int NT = K_DIM / 64;              // 64 K-tiles of BK=64
    constexpr int NBM = M_DIM / 256;            // 32
    constexpr int NWG = NBM * (N_DIM / 256);    // 1376, % 8 == 0

    __shared__ ushort_t sA[2][256 * 64];        // 2 x 32 KB
    __shared__ ushort_t sB[2][256 * 64];        // 2 x 32 KB  (128 KB total)

    // XCD-aware bijective swizzle
    int id = (blockIdx.x & 7) * (NWG / 8) + (blockIdx.x >> 3);
    const int bm = id & (NBM - 1);
    const int bn = id >> 5;

    const int tid = threadIdx.x;
    const int lane = tid & 63;
    const int w  = tid >> 6;     // wave 0..7
    const int wr = w >> 2;       // 0..1 (M)
    const int wc = w & 3;        // 0..3 (N)

    // ---- staging source (pre-swizzled global chunk: c_src = c_lds ^ (row&7)) ----
    const int trow = tid >> 3;                                   // 0..63
    const int scol = ((tid & 7) ^ (trow & 7)) * 8;               // XOR-swizzled source col
    const ushort_t* aBase = A + (size_t)(bm * 256 + trow) * K_DIM + scol;
    const ushort_t* bBase = B + (size_t)(bn * 256 + trow) * K_DIM + scol;
    const int ldsW = w * 512;                                    // wave-uniform dest (ushorts)

    // stage half H (128 rows) of K-tile kt into buffer sbuf (2 x GLD16/wave)
#define STAGE_A(kt, H, sbuf) do { if ((kt) < NT) { \
        const ushort_t* _s = aBase + (size_t)((H) * 128) * K_DIM + (kt) * 64; \
        ushort_t* _d = &sA[sbuf][(H) * 8192 + ldsW]; \
        GLD16(_s, _d); GLD16(_s + (size_t)64 * K_DIM, _d + 4096); } } while (0)
#define STAGE_B(kt, H, sbuf) do { if ((kt) < NT) { \
        const ushort_t* _s = bBase + (size_t)((H) * 128) * K_DIM + (kt) * 64; \
        ushort_t* _d = &sB[sbuf][(H) * 8192 + ldsW]; \
        GLD16(_s, _d); GLD16(_s + (size_t)64 * K_DIM, _d + 4096); } } while (0)

    // ---- ds_read lane addressing (swizzled) ----
    const int rowAe = (wr * 16 + (lane & 15)) * 64;
    const int rowBe = (wc * 16 + (lane & 15)) * 64;
    const int cb  = lane >> 4;
    const int swz = lane & 7;

    s16x8 aF[4][2];          // current A-half: 4 m-frags x 2 kk
    s16x8 bF[2][2][2];       // BOTH B-halves resident: nh x 2 ii x 2 kk
    f32x4 acc[8][4];
#pragma unroll
    for (int j = 0; j < 8; ++j)
#pragma unroll
        for (int i = 0; i < 4; ++i) acc[j][i] = (f32x4){0.f, 0.f, 0.f, 0.f};

#define LDA(mh, buf) do { \
    _Pragma("unroll") for (int jj = 0; jj < 4; ++jj) \
    _Pragma("unroll") for (int kk = 0; kk < 2; ++kk) \
        aF[jj][kk] = *(const s16x8*)&sA[buf][(mh) * 8192 + jj * 2048 + rowAe + (((cb + kk * 4) ^ swz) * 8)]; \
    } while (0)
#define LDB(nh, buf) do { \
    _Pragma("unroll") for (int ii = 0; ii < 2; ++ii) \
    _Pragma("unroll") for (int kk = 0; kk < 2; ++kk) \
        bF[nh][ii][kk] = *(const s16x8*)&sB[buf][(nh) * 8192 + ii * 4096 + rowBe + (((cb + kk * 4) ^ swz) * 8)]; \
    } while (0)
#define MFMA_Q(mh, nh) do { \
    __builtin_amdgcn_s_setprio(1); \
    _Pragma("unroll") for (int jj = 0; jj < 4; ++jj) \
    _Pragma("unroll") for (int ii = 0; ii < 2; ++ii) \
    _Pragma("unroll") for (int kk = 0; kk < 2; ++kk) \
        acc[(mh) * 4 + jj][(nh) * 2 + ii] = __builtin_amdgcn_mfma_f32_16x16x32_bf16( \
            aF[jj][kk], bF[nh][ii][kk], acc[(mh) * 4 + jj][(nh) * 2 + ii], 0, 0, 0); \
    __builtin_amdgcn_s_setprio(0); \
    } while (0)

    // ---- prologue: stage tile 0 then tile 1 (order matters for vmcnt) ----
    STAGE_A(0, 0, 0); STAGE_B(0, 0, 0); STAGE_B(0, 1, 0); STAGE_A(0, 1, 0);
    STAGE_A(1, 0, 1); STAGE_B(1, 0, 1); STAGE_B(1, 1, 1); STAGE_A(1, 1, 1);
    VMW8();          // tile 0 landed; tile 1's 8 loads in flight
    BAR();

    // ---- main loop: 4 phases / K-tile; group t stages tile t+2 into buf ----
    // phase (mh,nh): (0,0) (0,1) (1,1) (1,0); both B-halves live in regs
    // stage slots: P2: A0+B0(t+2)  P3: B1(t+2)  P4: A1(t+2)
    //   (each target half last read one phase earlier -> dead across a barrier)
#define GROUP(g, buf) do { \
        /* P1 */ LDA(0, buf); LDB(0, buf); \
                 BAR(); MFMA_Q(0, 0); BAR(); \
        /* P2 */ LDB(1, buf); STAGE_A((g) + 2, 0, buf); STAGE_B((g) + 2, 0, buf); \
                 BAR(); MFMA_Q(0, 1); BAR(); \
        /* P3 */ LDA(1, buf); STAGE_B((g) + 2, 1, buf); \
                 BAR(); MFMA_Q(1, 1); BAR(); \
        /* P4 */               STAGE_A((g) + 2, 1, buf); \
                 BAR(); MFMA_Q(1, 0); \
                 if ((g) >= NT - 2) { VMW0(); } else { VMW8(); } \
                 BAR(); \
    } while (0)

    for (int g = 0; g < NT; g += 2) {
        GROUP(g, 0);
        GROUP(g + 1, 1);
    }

    // ---- epilogue: C += bias ----
#pragma unroll
    for (int i = 0; i < 4; ++i) {
        const int col = bn * 256 + 16 * wc + 64 * i + (lane & 15);
        const float bv = bias[col];
#pragma unroll
        for (int j = 0; j < 8; ++j) {
            const int row = bm * 256 + 16 * wr + 32 * j + ((lane >> 4) << 2);
            float* cp = C + (size_t)row * N_DIM + col;
#pragma unroll
            for (int r = 0; r < 4; ++r)
                cp[(size_t)r * N_DIM] = acc[j][i][r] + bv;
        }
    }
#undef GROUP
#undef MFMA_Q
#undef LDA
#undef LDB
#undef STAGE_A
#undef STAGE_B
}

// ---------- fallback (ws too small): classic 16x16 fp32 tiled GEMM ----------
__global__ __launch_bounds__(256) void k_fb(const float* __restrict__ x, const int* __restrict__ q,
                                            const float* __restrict__ sc, const float* __restrict__ zp,
                                            const float* __restrict__ bias, float* __restrict__ C) {
    __shared__ float sX[16][17];
    __shared__ float sW[16][17];
    int tx = threadIdx.x & 15, ty = threadIdx.x >> 4;
    int m0 = blockIdx.y * 16, n0 = blockIdx.x * 16;
    int o = n0 + ty;
    float s = sc[o], z = zp[o];
    float acc = 0.f;
    for (int k0 = 0; k0 < K_DIM; k0 += 16) {
        sX[ty][tx] = x[(size_t)(m0 + ty) * K_DIM + k0 + tx];
        sW[ty][tx] = ((float)q[(size_t)o * K_DIM + k0 + tx] - z) * s;
        __syncthreads();
#pragma unroll
        for (int kk = 0; kk < 16; ++kk) acc += sX[ty][kk] * sW[tx][kk];
        __syncthreads();
    }
    C[(size_t)(m0 + ty) * N_DIM + n0 + tx] = acc + bias[n0 + tx];
}

extern "C" void kernel_launch(void* const* d_in, const int* in_sizes, int n_in,
                              void* d_out, int out_size, void* d_ws, size_t ws_size,
                              hipStream_t stream) {
    const float* x    = (const float*)d_in[0];
    const int*   qw   = (const int*)d_in[1];
    const float* sc   = (const float*)d_in[2];
    const float* zp   = (const float*)d_in[3];
    const float* bias = (const float*)d_in[4];
    float* out = (float*)d_out;

    const size_t xb_bytes = (size_t)M_DIM * K_DIM * 2;
    const size_t wb_bytes = (size_t)N_DIM * K_DIM * 2;
    if (ws_size >= xb_bytes + wb_bytes) {
        unsigned short* xb = (unsigned short*)d_ws;
        unsigned short* wb = xb + (size_t)M_DIM * K_DIM;
        k_cvt_x<<<(M_DIM * K_DIM / 8) / 256, 256, 0, stream>>>((const float4*)x, (uint4*)xb);
        k_deq<<<(N_DIM * K_DIM / 8) / 256, 256, 0, stream>>>((const int4*)qw, sc, zp, (uint4*)wb);
        k_gemm<<<(M_DIM / 256) * (N_DIM / 256), 512, 0, stream>>>(xb, wb, bias, out);
    } else {
        dim3 g(N_DIM / 16, M_DIM / 16);
        k_fb<<<g, 256, 0, stream>>>(x, qw, sc, zp, bias, out);
    }
}